// Round 2
// baseline (2128.597 us; speedup 1.0000x reference)
//
#include <hip/hip_runtime.h>
#include <math.h>

#define NB 16
#define NPTS 2048
#define DIN 1280
#define DM 256
#define BNROWS (NB * NPTS)   // 32768

// ---------------------------------------------------------------------------
// Positional embedding value for output channel c given xyz (c in [0,256)).
// d<252: coord=c/84, f=c%84, j=f>>1, freq=10000^(2j/84),
//        val = xyz[coord]*2*pi/freq; even f -> sin, odd f -> cos.  d>=252: 0.
// ---------------------------------------------------------------------------
static __device__ __forceinline__ float pos_val(int c, float x, float y, float z) {
    if (c >= 252) return 0.0f;
    const int coord = c / 84;
    const int f = c - coord * 84;
    const int j = f >> 1;
    const float xc = (coord == 0) ? x : ((coord == 1) ? y : z);
    // freq = 10000^(2j/84) = exp(ln(10000) * 2j / 84)
    const float freq = expf((float)(2 * j) * (9.210340371976184f / 84.0f));
    const float v = xc * 6.283185307179586f / freq;
    return (f & 1) ? cosf(v) : sinf(v);
}

// ---------------------------------------------------------------------------
// proj_kernel: out = A(M x 1280) @ W(1280 x 256) + bias, then
//   logits[row] += sum_c out_pre_pos[row][c] * Wc[c]   (atomic, partial per block)
//   out[row][c] += pos_embed(xyz[row], c)
// grid (M/64, 256/64), block 256.  4x4 register tile per thread.
// ---------------------------------------------------------------------------
__global__ __launch_bounds__(256)
void proj_kernel(const float* __restrict__ A, const float* __restrict__ W,
                 const float* __restrict__ bias, const float* __restrict__ Wc,
                 const float* __restrict__ xyz, float* __restrict__ out,
                 float* __restrict__ logits)
{
    __shared__ float As[16][68];  // [k][m], padded
    __shared__ float Ws[16][64];  // [k][n]
    const int m0 = blockIdx.x * 64;
    const int n0 = blockIdx.y * 64;
    const int t  = threadIdx.x;
    const int tx = t & 15, ty = t >> 4;
    const int lm = t >> 2, lk = (t & 3) * 4;   // A-tile load coords
    const int lw = t >> 4, ln = (t & 15) * 4;  // W-tile load coords

    float acc[4][4] = {};

    for (int k0 = 0; k0 < DIN; k0 += 16) {
        float4 a4 = *(const float4*)(A + (size_t)(m0 + lm) * DIN + k0 + lk);
        float4 w4 = *(const float4*)(W + (size_t)(k0 + lw) * DM + n0 + ln);
        As[lk + 0][lm] = a4.x; As[lk + 1][lm] = a4.y;
        As[lk + 2][lm] = a4.z; As[lk + 3][lm] = a4.w;
        *(float4*)&Ws[lw][ln] = w4;
        __syncthreads();
        #pragma unroll
        for (int kk = 0; kk < 16; ++kk) {
            const float4 av = *(const float4*)&As[kk][ty * 4];
            const float4 wv = *(const float4*)&Ws[kk][tx * 4];
            const float aa[4] = {av.x, av.y, av.z, av.w};
            const float ww[4] = {wv.x, wv.y, wv.z, wv.w};
            #pragma unroll
            for (int i = 0; i < 4; ++i)
                #pragma unroll
                for (int j = 0; j < 4; ++j)
                    acc[i][j] = fmaf(aa[i], ww[j], acc[i][j]);
        }
        __syncthreads();
    }

    // epilogue
    #pragma unroll
    for (int i = 0; i < 4; ++i) {
        const int row = m0 + ty * 4 + i;
        float vals[4];
        float wpart = 0.0f;
        #pragma unroll
        for (int j = 0; j < 4; ++j) {
            const int col = n0 + tx * 4 + j;
            const float s = acc[i][j] + bias[col];
            vals[j] = s;
            wpart = fmaf(s, Wc[col], wpart);   // confidence logit uses PRE-pos value
        }
        #pragma unroll
        for (int off = 1; off < 16; off <<= 1)
            wpart += __shfl_xor(wpart, off);
        if (tx == 0) atomicAdd(&logits[row], wpart);

        const float px = xyz[(size_t)row * 3 + 0];
        const float py = xyz[(size_t)row * 3 + 1];
        const float pz = xyz[(size_t)row * 3 + 2];
        float4 o;
        o.x = vals[0] + pos_val(n0 + tx * 4 + 0, px, py, pz);
        o.y = vals[1] + pos_val(n0 + tx * 4 + 1, px, py, pz);
        o.z = vals[2] + pos_val(n0 + tx * 4 + 2, px, py, pz);
        o.w = vals[3] + pos_val(n0 + tx * 4 + 3, px, py, pz);
        *(float4*)(out + (size_t)row * DM + n0 + tx * 4) = o;
    }
}

// ---------------------------------------------------------------------------
// gemm_qk: out = (A(M x 256) @ W(256 x 256) + bias) * alpha
// ---------------------------------------------------------------------------
__global__ __launch_bounds__(256)
void gemm_qk(const float* __restrict__ A, const float* __restrict__ W,
             const float* __restrict__ bias, const float alpha,
             float* __restrict__ out)
{
    __shared__ float As[16][68];
    __shared__ float Ws[16][64];
    const int m0 = blockIdx.x * 64;
    const int n0 = blockIdx.y * 64;
    const int t  = threadIdx.x;
    const int tx = t & 15, ty = t >> 4;
    const int lm = t >> 2, lk = (t & 3) * 4;
    const int lw = t >> 4, ln = (t & 15) * 4;

    float acc[4][4] = {};

    for (int k0 = 0; k0 < DM; k0 += 16) {
        float4 a4 = *(const float4*)(A + (size_t)(m0 + lm) * DM + k0 + lk);
        float4 w4 = *(const float4*)(W + (size_t)(k0 + lw) * DM + n0 + ln);
        As[lk + 0][lm] = a4.x; As[lk + 1][lm] = a4.y;
        As[lk + 2][lm] = a4.z; As[lk + 3][lm] = a4.w;
        *(float4*)&Ws[lw][ln] = w4;
        __syncthreads();
        #pragma unroll
        for (int kk = 0; kk < 16; ++kk) {
            const float4 av = *(const float4*)&As[kk][ty * 4];
            const float4 wv = *(const float4*)&Ws[kk][tx * 4];
            const float aa[4] = {av.x, av.y, av.z, av.w};
            const float ww[4] = {wv.x, wv.y, wv.z, wv.w};
            #pragma unroll
            for (int i = 0; i < 4; ++i)
                #pragma unroll
                for (int j = 0; j < 4; ++j)
                    acc[i][j] = fmaf(aa[i], ww[j], acc[i][j]);
        }
        __syncthreads();
    }

    #pragma unroll
    for (int i = 0; i < 4; ++i) {
        const int row = m0 + ty * 4 + i;
        float4 o;
        o.x = (acc[i][0] + bias[n0 + tx * 4 + 0]) * alpha;
        o.y = (acc[i][1] + bias[n0 + tx * 4 + 1]) * alpha;
        o.z = (acc[i][2] + bias[n0 + tx * 4 + 2]) * alpha;
        o.w = (acc[i][3] + bias[n0 + tx * 4 + 3]) * alpha;
        *(float4*)(out + (size_t)row * DM + n0 + tx * 4) = o;
    }
}

// ---------------------------------------------------------------------------
// sigmoid_kernel: w[i] = sigmoid(w[i] + bc[0])
// ---------------------------------------------------------------------------
__global__ __launch_bounds__(256)
void sigmoid_kernel(float* __restrict__ w, const float* __restrict__ bc, int n)
{
    const int i = blockIdx.x * 256 + threadIdx.x;
    if (i < n) {
        const float z = w[i] + bc[0];
        w[i] = 1.0f / (1.0f + expf(-z));
    }
}

// ---------------------------------------------------------------------------
// attn_kernel: flash-style attention with value = xyz (3 dims).
//   corr[b,q,:] = softmax_s(Q[b,q,:].K[b,s,:]) @ V[b,s,:]
// Per block: 128 queries, loop key tiles of 128, d-chunks of 32 staged in LDS.
// Thread (tx,ty) of 16x16 owns an 8x8 logit micro-tile; keeps per-row partial
// online-softmax state over its own key columns; merged across tx at the end.
// grid (NPTS/128, NB), block 256.
// ---------------------------------------------------------------------------
__global__ __launch_bounds__(256)
void attn_kernel(const float* __restrict__ Q, const float* __restrict__ K,
                 const float* __restrict__ V, float* __restrict__ corr)
{
    __shared__ float Qc[32][132];  // [d][point], padded
    __shared__ float Kc[32][132];
    const int b  = blockIdx.y;
    const int q0 = blockIdx.x * 128;
    const float* Qb = Q + (size_t)b * NPTS * DM;
    const float* Kb = K + (size_t)b * NPTS * DM;
    const float* Vb = V + (size_t)b * NPTS * 3;
    const int t  = threadIdx.x;
    const int tx = t & 15, ty = t >> 4;

    float m[8], l[8], a0[8], a1[8], a2[8];
    #pragma unroll
    for (int i = 0; i < 8; ++i) { m[i] = -1e30f; l[i] = 0.f; a0[i] = 0.f; a1[i] = 0.f; a2[i] = 0.f; }

    for (int kt = 0; kt < NPTS; kt += 128) {
        float L[8][8];
        #pragma unroll
        for (int i = 0; i < 8; ++i)
            #pragma unroll
            for (int j = 0; j < 8; ++j) L[i][j] = 0.f;

        for (int d0 = 0; d0 < DM; d0 += 32) {
            __syncthreads();
            #pragma unroll
            for (int it = 0; it < 4; ++it) {
                const int f  = t + it * 256;   // 0..1023 float4 slots
                const int pt = f >> 3;         // 0..127
                const int dd = (f & 7) << 2;   // 0,4,...,28
                const float4 qv = *(const float4*)(Qb + (size_t)(q0 + pt) * DM + d0 + dd);
                const float4 kv = *(const float4*)(Kb + (size_t)(kt + pt) * DM + d0 + dd);
                Qc[dd + 0][pt] = qv.x; Qc[dd + 1][pt] = qv.y;
                Qc[dd + 2][pt] = qv.z; Qc[dd + 3][pt] = qv.w;
                Kc[dd + 0][pt] = kv.x; Kc[dd + 1][pt] = kv.y;
                Kc[dd + 2][pt] = kv.z; Kc[dd + 3][pt] = kv.w;
            }
            __syncthreads();
            #pragma unroll 4
            for (int d = 0; d < 32; ++d) {
                const float4 qa = *(const float4*)&Qc[d][ty * 8];
                const float4 qb = *(const float4*)&Qc[d][ty * 8 + 4];
                const float4 ka = *(const float4*)&Kc[d][tx * 8];
                const float4 kb = *(const float4*)&Kc[d][tx * 8 + 4];
                const float q8[8] = {qa.x, qa.y, qa.z, qa.w, qb.x, qb.y, qb.z, qb.w};
                const float k8[8] = {ka.x, ka.y, ka.z, ka.w, kb.x, kb.y, kb.z, kb.w};
                #pragma unroll
                for (int i = 0; i < 8; ++i)
                    #pragma unroll
                    for (int j = 0; j < 8; ++j)
                        L[i][j] = fmaf(q8[i], k8[j], L[i][j]);
            }
        }

        // online softmax update over this thread's 8 key columns
        #pragma unroll
        for (int i = 0; i < 8; ++i) {
            float tm = L[i][0];
            #pragma unroll
            for (int j = 1; j < 8; ++j) tm = fmaxf(tm, L[i][j]);
            const float M = fmaxf(m[i], tm);
            const float c = __expf(m[i] - M);
            float sl = 0.f, s0 = 0.f, s1 = 0.f, s2 = 0.f;
            #pragma unroll
            for (int j = 0; j < 8; ++j) {
                const float p = __expf(L[i][j] - M);
                const int key = kt + tx * 8 + j;
                sl += p;
                s0 = fmaf(p, Vb[(size_t)key * 3 + 0], s0);
                s1 = fmaf(p, Vb[(size_t)key * 3 + 1], s1);
                s2 = fmaf(p, Vb[(size_t)key * 3 + 2], s2);
            }
            m[i] = M;
            l[i]  = l[i]  * c + sl;
            a0[i] = a0[i] * c + s0;
            a1[i] = a1[i] * c + s1;
            a2[i] = a2[i] * c + s2;
        }
    }

    // merge partial states across the 16 tx lanes (same query rows)
    #pragma unroll
    for (int off = 1; off < 16; off <<= 1) {
        #pragma unroll
        for (int i = 0; i < 8; ++i) {
            const float mo = __shfl_xor(m[i], off);
            const float lo = __shfl_xor(l[i], off);
            const float b0 = __shfl_xor(a0[i], off);
            const float b1 = __shfl_xor(a1[i], off);
            const float b2 = __shfl_xor(a2[i], off);
            const float M  = fmaxf(m[i], mo);
            const float c1 = __expf(m[i] - M);
            const float c2 = __expf(mo - M);
            m[i]  = M;
            l[i]  = l[i]  * c1 + lo * c2;
            a0[i] = a0[i] * c1 + b0 * c2;
            a1[i] = a1[i] * c1 + b1 * c2;
            a2[i] = a2[i] * c1 + b2 * c2;
        }
    }
    if (tx == 0) {
        #pragma unroll
        for (int i = 0; i < 8; ++i) {
            const int row = q0 + ty * 8 + i;
            const float inv = 1.0f / l[i];
            corr[(size_t)(b * NPTS + row) * 3 + 0] = a0[i] * inv;
            corr[(size_t)(b * NPTS + row) * 3 + 1] = a1[i] * inv;
            corr[(size_t)(b * NPTS + row) * 3 + 2] = a2[i] * inv;
        }
    }
}

// ---------------------------------------------------------------------------
// reduce_kernel: per batch, compute S = [sum w, sum w*a(3), sum w*b(3),
//                                        sum w*a_r*b_c (9)]  (double)
// a = concat(xyz1, tgt_corr), b = concat(src_corr, xyz2), w = concat(sw, tw)
// grid NB, block 256.
// ---------------------------------------------------------------------------
__global__ __launch_bounds__(256)
void reduce_kernel(const float* __restrict__ xyz1, const float* __restrict__ xyz2,
                   const float* __restrict__ scorr, const float* __restrict__ tcorr,
                   const float* __restrict__ srcw, const float* __restrict__ tgtw,
                   double* __restrict__ bsums)
{
    const int b = blockIdx.x;
    const int t = threadIdx.x;
    double s[16];
    #pragma unroll
    for (int k = 0; k < 16; ++k) s[k] = 0.0;

    for (int i = t; i < 2 * NPTS; i += 256) {
        float ax, ay, az, bx, by, bz, w;
        if (i < NPTS) {
            const size_t o = ((size_t)b * NPTS + i) * 3;
            ax = xyz1[o]; ay = xyz1[o + 1]; az = xyz1[o + 2];
            bx = scorr[o]; by = scorr[o + 1]; bz = scorr[o + 2];
            w = srcw[b * NPTS + i];
        } else {
            const int ii = i - NPTS;
            const size_t o = ((size_t)b * NPTS + ii) * 3;
            ax = tcorr[o]; ay = tcorr[o + 1]; az = tcorr[o + 2];
            bx = xyz2[o]; by = xyz2[o + 1]; bz = xyz2[o + 2];
            w = tgtw[b * NPTS + ii];
        }
        const double dw = (double)w;
        const double dax = ax, day = ay, daz = az;
        const double dbx = bx, dby = by, dbz = bz;
        s[0] += dw;
        s[1] += dw * dax; s[2] += dw * day; s[3] += dw * daz;
        s[4] += dw * dbx; s[5] += dw * dby; s[6] += dw * dbz;
        s[7]  += dw * dax * dbx; s[8]  += dw * dax * dby; s[9]  += dw * dax * dbz;
        s[10] += dw * day * dbx; s[11] += dw * day * dby; s[12] += dw * day * dbz;
        s[13] += dw * daz * dbx; s[14] += dw * daz * dby; s[15] += dw * daz * dbz;
    }

    __shared__ double red[256][16];
    #pragma unroll
    for (int k = 0; k < 16; ++k) red[t][k] = s[k];
    __syncthreads();
    for (int step = 128; step >= 1; step >>= 1) {
        if (t < step) {
            #pragma unroll
            for (int k = 0; k < 16; ++k) red[t][k] += red[t + step][k];
        }
        __syncthreads();
    }
    if (t == 0) {
        #pragma unroll
        for (int k = 0; k < 16; ++k) bsums[b * 16 + k] = red[0][k];
    }
}

// ---------------------------------------------------------------------------
// svd_kernel: per batch weighted Kabsch via double-precision Jacobi SVD(3x3).
// ---------------------------------------------------------------------------
__global__ void svd_kernel(const double* __restrict__ bsums, float* __restrict__ out)
{
    const int b = threadIdx.x;
    if (b >= NB) return;
    const double* s = bsums + b * 16;
    double Wd = s[0];
    if (Wd < 1e-6) Wd = 1e-6;
    const double inv = 1.0 / Wd;

    double ca[3], cb[3];
    for (int r = 0; r < 3; ++r) { ca[r] = s[1 + r] * inv; cb[r] = s[4 + r] * inv; }
    double cov[3][3];
    for (int r = 0; r < 3; ++r)
        for (int c = 0; c < 3; ++c)
            cov[r][c] = s[7 + r * 3 + c] * inv - ca[r] * cb[c];

    // M = cov^T cov (symmetric PSD)
    double Mm[3][3];
    for (int i = 0; i < 3; ++i)
        for (int j = 0; j < 3; ++j)
            Mm[i][j] = cov[0][i] * cov[0][j] + cov[1][i] * cov[1][j] + cov[2][i] * cov[2][j];

    double Vm[3][3] = {{1, 0, 0}, {0, 1, 0}, {0, 0, 1}};
    const int PP[3] = {0, 0, 1}, QQ[3] = {1, 2, 2};
    for (int sweep = 0; sweep < 20; ++sweep) {
        for (int pi = 0; pi < 3; ++pi) {
            const int p = PP[pi], q = QQ[pi];
            const double apq = Mm[p][q];
            if (fabs(apq) < 1e-300) continue;
            const double tau = (Mm[q][q] - Mm[p][p]) / (2.0 * apq);
            const double tt = ((tau >= 0.0) ? 1.0 : -1.0) / (fabs(tau) + sqrt(1.0 + tau * tau));
            const double c = 1.0 / sqrt(1.0 + tt * tt);
            const double sn = tt * c;
            for (int k = 0; k < 3; ++k) {
                const double mkp = Mm[k][p], mkq = Mm[k][q];
                Mm[k][p] = c * mkp - sn * mkq;
                Mm[k][q] = sn * mkp + c * mkq;
            }
            for (int k = 0; k < 3; ++k) {
                const double mpk = Mm[p][k], mqk = Mm[q][k];
                Mm[p][k] = c * mpk - sn * mqk;
                Mm[q][k] = sn * mpk + c * mqk;
            }
            for (int k = 0; k < 3; ++k) {
                const double vkp = Vm[k][p], vkq = Vm[k][q];
                Vm[k][p] = c * vkp - sn * vkq;
                Vm[k][q] = sn * vkp + c * vkq;
            }
        }
    }

    double l0 = Mm[0][0], l1 = Mm[1][1], l2 = Mm[2][2];
    double v0[3], v1[3], v2[3];
    for (int k = 0; k < 3; ++k) { v0[k] = Vm[k][0]; v1[k] = Vm[k][1]; v2[k] = Vm[k][2]; }
    // sort eigenvalues descending (with vectors)
    if (l0 < l1) { double tmp = l0; l0 = l1; l1 = tmp;
        for (int k = 0; k < 3; ++k) { double tv = v0[k]; v0[k] = v1[k]; v1[k] = tv; } }
    if (l0 < l2) { double tmp = l0; l0 = l2; l2 = tmp;
        for (int k = 0; k < 3; ++k) { double tv = v0[k]; v0[k] = v2[k]; v2[k] = tv; } }
    if (l1 < l2) { double tmp = l1; l1 = l2; l2 = tmp;
        for (int k = 0; k < 3; ++k) { double tv = v1[k]; v1[k] = v2[k]; v2[k] = tv; } }

    // left singular vectors: u_i = cov v_i / s_i, orthonormalized; u2 = u0 x u1
    double u0[3], u1[3], u2[3];
    for (int r = 0; r < 3; ++r) u0[r] = cov[r][0] * v0[0] + cov[r][1] * v0[1] + cov[r][2] * v0[2];
    for (int r = 0; r < 3; ++r) u1[r] = cov[r][0] * v1[0] + cov[r][1] * v1[1] + cov[r][2] * v1[2];
    double n0 = sqrt(u0[0] * u0[0] + u0[1] * u0[1] + u0[2] * u0[2]);
    if (n0 > 1e-30) { for (int k = 0; k < 3; ++k) u0[k] /= n0; }
    else { u0[0] = 1; u0[1] = 0; u0[2] = 0; }
    const double d01 = u0[0] * u1[0] + u0[1] * u1[1] + u0[2] * u1[2];
    for (int k = 0; k < 3; ++k) u1[k] -= d01 * u0[k];
    double n1 = sqrt(u1[0] * u1[0] + u1[1] * u1[1] + u1[2] * u1[2]);
    if (n1 > 1e-30) { for (int k = 0; k < 3; ++k) u1[k] /= n1; }
    else {
        const double aa0 = fabs(u0[0]), aa1 = fabs(u0[1]), aa2 = fabs(u0[2]);
        const int ax = (aa0 <= aa1 && aa0 <= aa2) ? 0 : ((aa1 <= aa2) ? 1 : 2);
        double e[3] = {0, 0, 0}; e[ax] = 1.0;
        const double d = u0[ax];
        for (int k = 0; k < 3; ++k) u1[k] = e[k] - d * u0[k];
        const double nn = sqrt(u1[0] * u1[0] + u1[1] * u1[1] + u1[2] * u1[2]);
        for (int k = 0; k < 3; ++k) u1[k] /= nn;
    }
    u2[0] = u0[1] * u1[2] - u0[2] * u1[1];
    u2[1] = u0[2] * u1[0] - u0[0] * u1[2];
    u2[2] = u0[0] * u1[1] - u0[1] * u1[0];

    // R = V U^T; if det <= 0, negate third column of V (== flip third term)
    double R[3][3];
    for (int r = 0; r < 3; ++r)
        for (int c = 0; c < 3; ++c)
            R[r][c] = v0[r] * u0[c] + v1[r] * u1[c] + v2[r] * u2[c];
    const double det = R[0][0] * (R[1][1] * R[2][2] - R[1][2] * R[2][1])
                     - R[0][1] * (R[1][0] * R[2][2] - R[1][2] * R[2][0])
                     + R[0][2] * (R[1][0] * R[2][1] - R[1][1] * R[2][0]);
    if (det <= 0.0) {
        for (int r = 0; r < 3; ++r)
            for (int c = 0; c < 3; ++c)
                R[r][c] -= 2.0 * v2[r] * u2[c];
    }
    double tv[3];
    for (int r = 0; r < 3; ++r)
        tv[r] = cb[r] - (R[r][0] * ca[0] + R[r][1] * ca[1] + R[r][2] * ca[2]);

    for (int r = 0; r < 3; ++r) {
        out[b * 12 + r * 4 + 0] = (float)R[r][0];
        out[b * 12 + r * 4 + 1] = (float)R[r][1];
        out[b * 12 + r * 4 + 2] = (float)R[r][2];
        out[b * 12 + r * 4 + 3] = (float)tv[r];
    }
}

// ---------------------------------------------------------------------------
extern "C" void kernel_launch(void* const* d_in, const int* in_sizes, int n_in,
                              void* d_out, int out_size, void* d_ws, size_t ws_size,
                              hipStream_t stream)
{
    const float* feat1 = (const float*)d_in[0];
    const float* xyz1  = (const float*)d_in[1];
    const float* feat2 = (const float*)d_in[2];
    const float* xyz2  = (const float*)d_in[3];
    const float* Wf = (const float*)d_in[4];
    const float* bf = (const float*)d_in[5];
    const float* Wq = (const float*)d_in[6];
    const float* bq = (const float*)d_in[7];
    const float* Wk = (const float*)d_in[8];
    const float* bk = (const float*)d_in[9];
    const float* Wc = (const float*)d_in[10];
    const float* bc = (const float*)d_in[11];
    float* out = (float*)d_out;

    // workspace layout (floats): ~135 MB total
    float* ws    = (float*)d_ws;
    float* src2  = ws;                                  // 32768*256
    float* tgt2  = src2  + (size_t)BNROWS * DM;
    float* qbuf  = tgt2  + (size_t)BNROWS * DM;
    float* kbuf  = qbuf  + (size_t)BNROWS * DM;
    float* srcw  = kbuf  + (size_t)BNROWS * DM;         // 32768 (logits then weights)
    float* tgtw  = srcw  + BNROWS;
    float* scorr = tgtw  + BNROWS;                      // 32768*3
    float* tcorr = scorr + (size_t)BNROWS * 3;
    double* bsums = (double*)(tcorr + (size_t)BNROWS * 3);  // 16*16 doubles (8B aligned)

    hipMemsetAsync(srcw, 0, 2 * BNROWS * sizeof(float), stream);

    const dim3 gproj(BNROWS / 64, DM / 64);   // (512, 4)
    proj_kernel<<<gproj, 256, 0, stream>>>(feat1, Wf, bf, Wc, xyz1, src2, srcw);
    proj_kernel<<<gproj, 256, 0, stream>>>(feat2, Wf, bf, Wc, xyz2, tgt2, tgtw);
    sigmoid_kernel<<<(2 * BNROWS) / 256, 256, 0, stream>>>(srcw, bc, 2 * BNROWS);

    const float scale = 1.0f / 16.0f;  // 1/sqrt(256)
    const dim3 gattn(NPTS / 128, NB);  // (16, 16)

    // direction 1: q from src2, k from tgt2, values xyz2 -> src_corr
    gemm_qk<<<gproj, 256, 0, stream>>>(src2, Wq, bq, scale, qbuf);
    gemm_qk<<<gproj, 256, 0, stream>>>(tgt2, Wk, bk, 1.0f, kbuf);
    attn_kernel<<<gattn, 256, 0, stream>>>(qbuf, kbuf, xyz2, scorr);

    // direction 2: q from tgt2, k from src2, values xyz1 -> tgt_corr
    gemm_qk<<<gproj, 256, 0, stream>>>(tgt2, Wq, bq, scale, qbuf);
    gemm_qk<<<gproj, 256, 0, stream>>>(src2, Wk, bk, 1.0f, kbuf);
    attn_kernel<<<gattn, 256, 0, stream>>>(qbuf, kbuf, xyz1, tcorr);

    reduce_kernel<<<NB, 256, 0, stream>>>(xyz1, xyz2, scorr, tcorr, srcw, tgtw, bsums);
    svd_kernel<<<1, 64, 0, stream>>>(bsums, out);
}

// Round 4
// 1293.498 us; speedup vs baseline: 1.6456x; 1.6456x over previous
//
#include <hip/hip_runtime.h>
#include <math.h>

#define NB 16
#define NPTS 2048
#define DIN 1280
#define DM 256
#define BNROWS (NB * NPTS)   // 32768

typedef __attribute__((ext_vector_type(8))) short bf16x8;   // 8 bf16 = 4 VGPRs
typedef __attribute__((ext_vector_type(4))) float f32x4;

// RNE float -> bf16 bits (inputs are finite; no NaN handling needed)
static __device__ __forceinline__ ushort f2bf(float f) {
    uint x = __float_as_uint(f);
    return (ushort)((x + 0x7FFF + ((x >> 16) & 1)) >> 16);
}

// ---------------------------------------------------------------------------
// Positional embedding value for output channel c given xyz (c in [0,256)).
// ---------------------------------------------------------------------------
static __device__ __forceinline__ float pos_val(int c, float x, float y, float z) {
    if (c >= 252) return 0.0f;
    const int coord = c / 84;
    const int f = c - coord * 84;
    const int j = f >> 1;
    const float xc = (coord == 0) ? x : ((coord == 1) ? y : z);
    const float freq = expf((float)(2 * j) * (9.210340371976184f / 84.0f));
    const float v = xc * 6.283185307179586f / freq;
    return (f & 1) ? cosf(v) : sinf(v);
}

// ---------------------------------------------------------------------------
// proj_kernel: out = A(M x 1280) @ W(1280 x 256) + bias (+pos emb), and
// confidence logits via atomics.
// ---------------------------------------------------------------------------
__global__ __launch_bounds__(256)
void proj_kernel(const float* __restrict__ A, const float* __restrict__ W,
                 const float* __restrict__ bias, const float* __restrict__ Wc,
                 const float* __restrict__ xyz, float* __restrict__ out,
                 float* __restrict__ logits)
{
    __shared__ float As[16][68];
    __shared__ float Ws[16][64];
    const int m0 = blockIdx.x * 64;
    const int n0 = blockIdx.y * 64;
    const int t  = threadIdx.x;
    const int tx = t & 15, ty = t >> 4;
    const int lm = t >> 2, lk = (t & 3) * 4;
    const int lw = t >> 4, ln = (t & 15) * 4;

    float acc[4][4] = {};

    for (int k0 = 0; k0 < DIN; k0 += 16) {
        float4 a4 = *(const float4*)(A + (size_t)(m0 + lm) * DIN + k0 + lk);
        float4 w4 = *(const float4*)(W + (size_t)(k0 + lw) * DM + n0 + ln);
        As[lk + 0][lm] = a4.x; As[lk + 1][lm] = a4.y;
        As[lk + 2][lm] = a4.z; As[lk + 3][lm] = a4.w;
        *(float4*)&Ws[lw][ln] = w4;
        __syncthreads();
        #pragma unroll
        for (int kk = 0; kk < 16; ++kk) {
            const float4 av = *(const float4*)&As[kk][ty * 4];
            const float4 wv = *(const float4*)&Ws[kk][tx * 4];
            const float aa[4] = {av.x, av.y, av.z, av.w};
            const float ww[4] = {wv.x, wv.y, wv.z, wv.w};
            #pragma unroll
            for (int i = 0; i < 4; ++i)
                #pragma unroll
                for (int j = 0; j < 4; ++j)
                    acc[i][j] = fmaf(aa[i], ww[j], acc[i][j]);
        }
        __syncthreads();
    }

    #pragma unroll
    for (int i = 0; i < 4; ++i) {
        const int row = m0 + ty * 4 + i;
        float vals[4];
        float wpart = 0.0f;
        #pragma unroll
        for (int j = 0; j < 4; ++j) {
            const int col = n0 + tx * 4 + j;
            const float s = acc[i][j] + bias[col];
            vals[j] = s;
            wpart = fmaf(s, Wc[col], wpart);
        }
        #pragma unroll
        for (int off = 1; off < 16; off <<= 1)
            wpart += __shfl_xor(wpart, off);
        if (tx == 0) atomicAdd(&logits[row], wpart);

        const float px = xyz[(size_t)row * 3 + 0];
        const float py = xyz[(size_t)row * 3 + 1];
        const float pz = xyz[(size_t)row * 3 + 2];
        float4 o;
        o.x = vals[0] + pos_val(n0 + tx * 4 + 0, px, py, pz);
        o.y = vals[1] + pos_val(n0 + tx * 4 + 1, px, py, pz);
        o.z = vals[2] + pos_val(n0 + tx * 4 + 2, px, py, pz);
        o.w = vals[3] + pos_val(n0 + tx * 4 + 3, px, py, pz);
        *(float4*)(out + (size_t)row * DM + n0 + tx * 4) = o;
    }
}

// ---------------------------------------------------------------------------
// gemm_qk_bf16: out = bf16((A(M x 256) @ W(256 x 256) + bias) * alpha)
// ---------------------------------------------------------------------------
__global__ __launch_bounds__(256)
void gemm_qk_bf16(const float* __restrict__ A, const float* __restrict__ W,
                  const float* __restrict__ bias, const float alpha,
                  ushort* __restrict__ out)
{
    __shared__ float As[16][68];
    __shared__ float Ws[16][64];
    const int m0 = blockIdx.x * 64;
    const int n0 = blockIdx.y * 64;
    const int t  = threadIdx.x;
    const int tx = t & 15, ty = t >> 4;
    const int lm = t >> 2, lk = (t & 3) * 4;
    const int lw = t >> 4, ln = (t & 15) * 4;

    float acc[4][4] = {};

    for (int k0 = 0; k0 < DM; k0 += 16) {
        float4 a4 = *(const float4*)(A + (size_t)(m0 + lm) * DM + k0 + lk);
        float4 w4 = *(const float4*)(W + (size_t)(k0 + lw) * DM + n0 + ln);
        As[lk + 0][lm] = a4.x; As[lk + 1][lm] = a4.y;
        As[lk + 2][lm] = a4.z; As[lk + 3][lm] = a4.w;
        *(float4*)&Ws[lw][ln] = w4;
        __syncthreads();
        #pragma unroll
        for (int kk = 0; kk < 16; ++kk) {
            const float4 av = *(const float4*)&As[kk][ty * 4];
            const float4 wv = *(const float4*)&Ws[kk][tx * 4];
            const float aa[4] = {av.x, av.y, av.z, av.w};
            const float ww[4] = {wv.x, wv.y, wv.z, wv.w};
            #pragma unroll
            for (int i = 0; i < 4; ++i)
                #pragma unroll
                for (int j = 0; j < 4; ++j)
                    acc[i][j] = fmaf(aa[i], ww[j], acc[i][j]);
        }
        __syncthreads();
    }

    #pragma unroll
    for (int i = 0; i < 4; ++i) {
        const int row = m0 + ty * 4 + i;
        ushort4 o;
        o.x = f2bf((acc[i][0] + bias[n0 + tx * 4 + 0]) * alpha);
        o.y = f2bf((acc[i][1] + bias[n0 + tx * 4 + 1]) * alpha);
        o.z = f2bf((acc[i][2] + bias[n0 + tx * 4 + 2]) * alpha);
        o.w = f2bf((acc[i][3] + bias[n0 + tx * 4 + 3]) * alpha);
        *(ushort4*)(out + (size_t)row * DM + n0 + tx * 4) = o;
    }
}

// ---------------------------------------------------------------------------
// sigmoid_kernel: w[i] = sigmoid(w[i] + bc[0])
// ---------------------------------------------------------------------------
__global__ __launch_bounds__(256)
void sigmoid_kernel(float* __restrict__ w, const float* __restrict__ bc, int n)
{
    const int i = blockIdx.x * 256 + threadIdx.x;
    if (i < n) {
        const float z = w[i] + bc[0];
        w[i] = 1.0f / (1.0f + expf(-z));
    }
}

// ---------------------------------------------------------------------------
// attn_mfma: MFMA flash attention, value = xyz (3 dims), fixed-shift softmax.
//   acc4[b,q,{l,x,y,z}] += sum over this block's keys of
//       p = exp(logit - 16),  p*Vx, p*Vy, p*Vz      (atomic)
// Q rows pre-scaled by 1/sqrt(D).  No LDS, no barriers.
// Block = 256 thr = 4 waves; wave owns 64 queries (4 MFMA A-tiles held in
// registers); loops 512 keys (blockIdx.z quarter) in 16-key MFMA tiles.
// Each K fragment is reused by 4 MFMAs -> K-feed ~53 B/cyc/CU < L2 budget.
// mfma_f32_16x16x32_bf16: D[row=(lane>>4)*4+reg][col=lane&15] (HW-verified);
// A/B share the same lane->k mapping so any k-permutation cancels.
// grid (NPTS/256, NB, 4), block 256.
// ---------------------------------------------------------------------------
__global__ __launch_bounds__(256, 2)
void attn_mfma(const ushort* __restrict__ Q, const ushort* __restrict__ K,
               const float* __restrict__ V, float* __restrict__ acc4)
{
    const int b    = blockIdx.y;
    const int lane = threadIdx.x & 63;
    const int wv   = threadIdx.x >> 6;
    const int col  = lane & 15;   // A-row / B-col lane index
    const int sub  = lane >> 4;   // k-subgroup (8 elems each)
    const int qbase = blockIdx.x * 256 + wv * 64;
    const int k0    = blockIdx.z * 512;

    const ushort* Qb = Q + (size_t)b * NPTS * DM;
    const ushort* Kb = K + (size_t)b * NPTS * DM;
    const float*  Vb = V + (size_t)b * NPTS * 3;

    // Q fragments: 4 sets (16 queries each) x 8 k-chunks, resident in VGPRs
    bf16x8 aq[4][8];
    #pragma unroll
    for (int s = 0; s < 4; ++s) {
        const ushort* qrow = Qb + (size_t)(qbase + s * 16 + col) * DM + sub * 8;
        #pragma unroll
        for (int c = 0; c < 8; ++c)
            aq[s][c] = *(const bf16x8*)(qrow + c * 32);
    }

    float lsum[4][4], ax[4][4], ay[4][4], az[4][4];
    #pragma unroll
    for (int s = 0; s < 4; ++s)
        #pragma unroll
        for (int r = 0; r < 4; ++r) {
            lsum[s][r] = 0.f; ax[s][r] = 0.f; ay[s][r] = 0.f; az[s][r] = 0.f;
        }

    for (int kt = k0; kt < k0 + 512; kt += 16) {
        const ushort* krow = Kb + (size_t)(kt + col) * DM + sub * 8;
        f32x4 sv0 = {0.f, 0.f, 0.f, 0.f};
        f32x4 sv1 = {0.f, 0.f, 0.f, 0.f};
        f32x4 sv2 = {0.f, 0.f, 0.f, 0.f};
        f32x4 sv3 = {0.f, 0.f, 0.f, 0.f};
        #pragma unroll
        for (int c = 0; c < 8; ++c) {
            const bf16x8 bk = *(const bf16x8*)(krow + c * 32);
            sv0 = __builtin_amdgcn_mfma_f32_16x16x32_bf16(aq[0][c], bk, sv0, 0, 0, 0);
            sv1 = __builtin_amdgcn_mfma_f32_16x16x32_bf16(aq[1][c], bk, sv1, 0, 0, 0);
            sv2 = __builtin_amdgcn_mfma_f32_16x16x32_bf16(aq[2][c], bk, sv2, 0, 0, 0);
            sv3 = __builtin_amdgcn_mfma_f32_16x16x32_bf16(aq[3][c], bk, sv3, 0, 0, 0);
        }
        // this lane's key column
        const float vx = Vb[(size_t)(kt + col) * 3 + 0];
        const float vy = Vb[(size_t)(kt + col) * 3 + 1];
        const float vz = Vb[(size_t)(kt + col) * 3 + 2];
        #pragma unroll
        for (int r = 0; r < 4; ++r) {
            const float p0 = __expf(sv0[r] - 16.0f);
            const float p1 = __expf(sv1[r] - 16.0f);
            const float p2 = __expf(sv2[r] - 16.0f);
            const float p3 = __expf(sv3[r] - 16.0f);
            lsum[0][r] += p0; ax[0][r] = fmaf(p0, vx, ax[0][r]);
            ay[0][r] = fmaf(p0, vy, ay[0][r]); az[0][r] = fmaf(p0, vz, az[0][r]);
            lsum[1][r] += p1; ax[1][r] = fmaf(p1, vx, ax[1][r]);
            ay[1][r] = fmaf(p1, vy, ay[1][r]); az[1][r] = fmaf(p1, vz, az[1][r]);
            lsum[2][r] += p2; ax[2][r] = fmaf(p2, vx, ax[2][r]);
            ay[2][r] = fmaf(p2, vy, ay[2][r]); az[2][r] = fmaf(p2, vz, az[2][r]);
            lsum[3][r] += p3; ax[3][r] = fmaf(p3, vx, ax[3][r]);
            ay[3][r] = fmaf(p3, vy, ay[3][r]); az[3][r] = fmaf(p3, vz, az[3][r]);
        }
    }

    // merge partials across the 16 key-column lanes (fixed shift => pure sums)
    #pragma unroll
    for (int off = 1; off < 16; off <<= 1) {
        #pragma unroll
        for (int s = 0; s < 4; ++s)
            #pragma unroll
            for (int r = 0; r < 4; ++r) {
                lsum[s][r] += __shfl_xor(lsum[s][r], off);
                ax[s][r]   += __shfl_xor(ax[s][r], off);
                ay[s][r]   += __shfl_xor(ay[s][r], off);
                az[s][r]   += __shfl_xor(az[s][r], off);
            }
    }
    if (col == 0) {
        #pragma unroll
        for (int s = 0; s < 4; ++s)
            #pragma unroll
            for (int r = 0; r < 4; ++r) {
                const int row = qbase + s * 16 + sub * 4 + r;
                float* dst = acc4 + ((size_t)b * NPTS + row) * 4;
                atomicAdd(dst + 0, lsum[s][r]);
                atomicAdd(dst + 1, ax[s][r]);
                atomicAdd(dst + 2, ay[s][r]);
                atomicAdd(dst + 3, az[s][r]);
            }
    }
}

// ---------------------------------------------------------------------------
// reduce_kernel: per batch, S = [sum w, sum w*a(3), sum w*b(3), sum w*a⊗b(9)]
// correspondences normalized inline from acc4 = {l, ax, ay, az}.
// ---------------------------------------------------------------------------
__global__ __launch_bounds__(256)
void reduce_kernel(const float* __restrict__ xyz1, const float* __restrict__ xyz2,
                   const float* __restrict__ sacc, const float* __restrict__ tacc,
                   const float* __restrict__ srcw, const float* __restrict__ tgtw,
                   double* __restrict__ bsums)
{
    const int b = blockIdx.x;
    const int t = threadIdx.x;
    double s[16];
    #pragma unroll
    for (int k = 0; k < 16; ++k) s[k] = 0.0;

    for (int i = t; i < 2 * NPTS; i += 256) {
        float ax_, ay_, az_, bx_, by_, bz_, w;
        if (i < NPTS) {
            const size_t row = (size_t)b * NPTS + i;
            ax_ = xyz1[row * 3]; ay_ = xyz1[row * 3 + 1]; az_ = xyz1[row * 3 + 2];
            const float4 s4 = *(const float4*)(sacc + row * 4);
            const float inv = 1.0f / s4.x;
            bx_ = s4.y * inv; by_ = s4.z * inv; bz_ = s4.w * inv;
            w = srcw[row];
        } else {
            const size_t row = (size_t)b * NPTS + (i - NPTS);
            const float4 t4 = *(const float4*)(tacc + row * 4);
            const float inv = 1.0f / t4.x;
            ax_ = t4.y * inv; ay_ = t4.z * inv; az_ = t4.w * inv;
            bx_ = xyz2[row * 3]; by_ = xyz2[row * 3 + 1]; bz_ = xyz2[row * 3 + 2];
            w = tgtw[row];
        }
        const double dw = (double)w;
        const double dax = ax_, day = ay_, daz = az_;
        const double dbx = bx_, dby = by_, dbz = bz_;
        s[0] += dw;
        s[1] += dw * dax; s[2] += dw * day; s[3] += dw * daz;
        s[4] += dw * dbx; s[5] += dw * dby; s[6] += dw * dbz;
        s[7]  += dw * dax * dbx; s[8]  += dw * dax * dby; s[9]  += dw * dax * dbz;
        s[10] += dw * day * dbx; s[11] += dw * day * dby; s[12] += dw * day * dbz;
        s[13] += dw * daz * dbx; s[14] += dw * daz * dby; s[15] += dw * daz * dbz;
    }

    __shared__ double red[256][16];
    #pragma unroll
    for (int k = 0; k < 16; ++k) red[t][k] = s[k];
    __syncthreads();
    for (int step = 128; step >= 1; step >>= 1) {
        if (t < step) {
            #pragma unroll
            for (int k = 0; k < 16; ++k) red[t][k] += red[t + step][k];
        }
        __syncthreads();
    }
    if (t == 0) {
        #pragma unroll
        for (int k = 0; k < 16; ++k) bsums[b * 16 + k] = red[0][k];
    }
}

// ---------------------------------------------------------------------------
// svd_kernel: per batch weighted Kabsch via double-precision Jacobi SVD(3x3).
// ---------------------------------------------------------------------------
__global__ void svd_kernel(const double* __restrict__ bsums, float* __restrict__ out)
{
    const int b = threadIdx.x;
    if (b >= NB) return;
    const double* s = bsums + b * 16;
    double Wd = s[0];
    if (Wd < 1e-6) Wd = 1e-6;
    const double inv = 1.0 / Wd;

    double ca[3], cb[3];
    for (int r = 0; r < 3; ++r) { ca[r] = s[1 + r] * inv; cb[r] = s[4 + r] * inv; }
    double cov[3][3];
    for (int r = 0; r < 3; ++r)
        for (int c = 0; c < 3; ++c)
            cov[r][c] = s[7 + r * 3 + c] * inv - ca[r] * cb[c];

    double Mm[3][3];
    for (int i = 0; i < 3; ++i)
        for (int j = 0; j < 3; ++j)
            Mm[i][j] = cov[0][i] * cov[0][j] + cov[1][i] * cov[1][j] + cov[2][i] * cov[2][j];

    double Vm[3][3] = {{1, 0, 0}, {0, 1, 0}, {0, 0, 1}};
    const int PP[3] = {0, 0, 1}, QQ[3] = {1, 2, 2};
    for (int sweep = 0; sweep < 20; ++sweep) {
        for (int pi = 0; pi < 3; ++pi) {
            const int p = PP[pi], q = QQ[pi];
            const double apq = Mm[p][q];
            if (fabs(apq) < 1e-300) continue;
            const double tau = (Mm[q][q] - Mm[p][p]) / (2.0 * apq);
            const double tt = ((tau >= 0.0) ? 1.0 : -1.0) / (fabs(tau) + sqrt(1.0 + tau * tau));
            const double c = 1.0 / sqrt(1.0 + tt * tt);
            const double sn = tt * c;
            for (int k = 0; k < 3; ++k) {
                const double mkp = Mm[k][p], mkq = Mm[k][q];
                Mm[k][p] = c * mkp - sn * mkq;
                Mm[k][q] = sn * mkp + c * mkq;
            }
            for (int k = 0; k < 3; ++k) {
                const double mpk = Mm[p][k], mqk = Mm[q][k];
                Mm[p][k] = c * mpk - sn * mqk;
                Mm[q][k] = sn * mpk + c * mqk;
            }
            for (int k = 0; k < 3; ++k) {
                const double vkp = Vm[k][p], vkq = Vm[k][q];
                Vm[k][p] = c * vkp - sn * vkq;
                Vm[k][q] = sn * vkp + c * vkq;
            }
        }
    }

    double l0 = Mm[0][0], l1 = Mm[1][1], l2 = Mm[2][2];
    double v0[3], v1[3], v2[3];
    for (int k = 0; k < 3; ++k) { v0[k] = Vm[k][0]; v1[k] = Vm[k][1]; v2[k] = Vm[k][2]; }
    if (l0 < l1) { double tmp = l0; l0 = l1; l1 = tmp;
        for (int k = 0; k < 3; ++k) { double tv = v0[k]; v0[k] = v1[k]; v1[k] = tv; } }
    if (l0 < l2) { double tmp = l0; l0 = l2; l2 = tmp;
        for (int k = 0; k < 3; ++k) { double tv = v0[k]; v0[k] = v2[k]; v2[k] = tv; } }
    if (l1 < l2) { double tmp = l1; l1 = l2; l2 = tmp;
        for (int k = 0; k < 3; ++k) { double tv = v1[k]; v1[k] = v2[k]; v2[k] = tv; } }

    double u0[3], u1[3], u2[3];
    for (int r = 0; r < 3; ++r) u0[r] = cov[r][0] * v0[0] + cov[r][1] * v0[1] + cov[r][2] * v0[2];
    for (int r = 0; r < 3; ++r) u1[r] = cov[r][0] * v1[0] + cov[r][1] * v1[1] + cov[r][2] * v1[2];
    double n0 = sqrt(u0[0] * u0[0] + u0[1] * u0[1] + u0[2] * u0[2]);
    if (n0 > 1e-30) { for (int k = 0; k < 3; ++k) u0[k] /= n0; }
    else { u0[0] = 1; u0[1] = 0; u0[2] = 0; }
    const double d01 = u0[0] * u1[0] + u0[1] * u1[1] + u0[2] * u1[2];
    for (int k = 0; k < 3; ++k) u1[k] -= d01 * u0[k];
    double n1 = sqrt(u1[0] * u1[0] + u1[1] * u1[1] + u1[2] * u1[2]);
    if (n1 > 1e-30) { for (int k = 0; k < 3; ++k) u1[k] /= n1; }
    else {
        const double aa0 = fabs(u0[0]), aa1 = fabs(u0[1]), aa2 = fabs(u0[2]);
        const int ax = (aa0 <= aa1 && aa0 <= aa2) ? 0 : ((aa1 <= aa2) ? 1 : 2);
        double e[3] = {0, 0, 0}; e[ax] = 1.0;
        const double d = u0[ax];
        for (int k = 0; k < 3; ++k) u1[k] = e[k] - d * u0[k];
        const double nn = sqrt(u1[0] * u1[0] + u1[1] * u1[1] + u1[2] * u1[2]);
        for (int k = 0; k < 3; ++k) u1[k] /= nn;
    }
    u2[0] = u0[1] * u1[2] - u0[2] * u1[1];
    u2[1] = u0[2] * u1[0] - u0[0] * u1[2];
    u2[2] = u0[0] * u1[1] - u0[1] * u1[0];

    double R[3][3];
    for (int r = 0; r < 3; ++r)
        for (int c = 0; c < 3; ++c)
            R[r][c] = v0[r] * u0[c] + v1[r] * u1[c] + v2[r] * u2[c];
    const double det = R[0][0] * (R[1][1] * R[2][2] - R[1][2] * R[2][1])
                     - R[0][1] * (R[1][0] * R[2][2] - R[1][2] * R[2][0])
                     + R[0][2] * (R[1][0] * R[2][1] - R[1][1] * R[2][0]);
    if (det <= 0.0) {
        for (int r = 0; r < 3; ++r)
            for (int c = 0; c < 3; ++c)
                R[r][c] -= 2.0 * v2[r] * u2[c];
    }
    double tv[3];
    for (int r = 0; r < 3; ++r)
        tv[r] = cb[r] - (R[r][0] * ca[0] + R[r][1] * ca[1] + R[r][2] * ca[2]);

    for (int r = 0; r < 3; ++r) {
        out[b * 12 + r * 4 + 0] = (float)R[r][0];
        out[b * 12 + r * 4 + 1] = (float)R[r][1];
        out[b * 12 + r * 4 + 2] = (float)R[r][2];
        out[b * 12 + r * 4 + 3] = (float)tv[r];
    }
}

// ---------------------------------------------------------------------------
extern "C" void kernel_launch(void* const* d_in, const int* in_sizes, int n_in,
                              void* d_out, int out_size, void* d_ws, size_t ws_size,
                              hipStream_t stream)
{
    const float* feat1 = (const float*)d_in[0];
    const float* xyz1  = (const float*)d_in[1];
    const float* feat2 = (const float*)d_in[2];
    const float* xyz2  = (const float*)d_in[3];
    const float* Wf = (const float*)d_in[4];
    const float* bf = (const float*)d_in[5];
    const float* Wq = (const float*)d_in[6];
    const float* bq = (const float*)d_in[7];
    const float* Wk = (const float*)d_in[8];
    const float* bk = (const float*)d_in[9];
    const float* Wc = (const float*)d_in[10];
    const float* bc = (const float*)d_in[11];
    float* out = (float*)d_out;

    // workspace layout
    float*  src2 = (float*)d_ws;                               // 32768*256 f32
    float*  tgt2 = src2 + (size_t)BNROWS * DM;                 // 32768*256 f32
    ushort* qbuf = (ushort*)(tgt2 + (size_t)BNROWS * DM);      // 32768*256 bf16
    ushort* kbuf = qbuf + (size_t)BNROWS * DM;                 // 32768*256 bf16
    float*  srcw = (float*)(kbuf + (size_t)BNROWS * DM);       // 32768 (zeroed)
    float*  tgtw = srcw + BNROWS;                              // 32768 (zeroed)
    float*  sacc = tgtw + BNROWS;                              // 32768*4 (zeroed)
    float*  tacc = sacc + (size_t)BNROWS * 4;                  // 32768*4 (zeroed)
    double* bsums = (double*)(tacc + (size_t)BNROWS * 4);      // 16*16 doubles

    // zero logits + attention accumulators (contiguous region)
    hipMemsetAsync(srcw, 0, (size_t)(2 * BNROWS + 8 * BNROWS) * sizeof(float), stream);

    const dim3 gproj(BNROWS / 64, DM / 64);   // (512, 4)
    proj_kernel<<<gproj, 256, 0, stream>>>(feat1, Wf, bf, Wc, xyz1, src2, srcw);
    proj_kernel<<<gproj, 256, 0, stream>>>(feat2, Wf, bf, Wc, xyz2, tgt2, tgtw);
    sigmoid_kernel<<<(2 * BNROWS) / 256, 256, 0, stream>>>(srcw, bc, 2 * BNROWS);

    const float scale = 1.0f / 16.0f;  // 1/sqrt(256)
    const dim3 gattn(NPTS / 256, NB, 4);  // (8, 16, 4) = 512 blocks

    // direction 1: q from src2, k from tgt2, values xyz2 -> sacc
    gemm_qk_bf16<<<gproj, 256, 0, stream>>>(src2, Wq, bq, scale, qbuf);
    gemm_qk_bf16<<<gproj, 256, 0, stream>>>(tgt2, Wk, bk, 1.0f, kbuf);
    attn_mfma<<<gattn, 256, 0, stream>>>(qbuf, kbuf, xyz2, sacc);

    // direction 2: q from tgt2, k from src2, values xyz1 -> tacc
    gemm_qk_bf16<<<gproj, 256, 0, stream>>>(tgt2, Wq, bq, scale, qbuf);
    gemm_qk_bf16<<<gproj, 256, 0, stream>>>(src2, Wk, bk, 1.0f, kbuf);
    attn_mfma<<<gattn, 256, 0, stream>>>(qbuf, kbuf, xyz1, tacc);

    reduce_kernel<<<NB, 256, 0, stream>>>(xyz1, xyz2, sacc, tacc, srcw, tgtw, bsums);
    svd_kernel<<<1, 64, 0, stream>>>(bsums, out);
}

// Round 5
// 759.504 us; speedup vs baseline: 2.8026x; 1.7031x over previous
//
#include <hip/hip_runtime.h>
#include <math.h>

#define NB 16
#define NPTS 2048
#define DIN 1280
#define DM 256
#define BNROWS (NB * NPTS)   // 32768

typedef __attribute__((ext_vector_type(8))) short bf16x8;   // 8 bf16 = 4 VGPRs
typedef __attribute__((ext_vector_type(4))) float f32x4;

// RNE float -> bf16 bits (inputs finite)
static __device__ __forceinline__ ushort f2bf(float f) {
    uint x = __float_as_uint(f);
    return (ushort)((x + 0x7FFF + ((x >> 16) & 1)) >> 16);
}

// pack 2 floats -> 2 bf16 in one u32 (gfx950 HW instruction, RNE)
static __device__ __forceinline__ uint cvtpk(float lo, float hi) {
    uint r;
    asm("v_cvt_pk_bf16_f32 %0, %1, %2" : "=v"(r) : "v"(lo), "v"(hi));
    return r;
}

// ---------------------------------------------------------------------------
// convert_wt: Wt[n][k] = bf16(W[k][n])  (transpose so B-fragments are k-contig)
// ---------------------------------------------------------------------------
__global__ __launch_bounds__(256)
void convert_wt(const float* __restrict__ W, ushort* __restrict__ Wt,
                const int K, const int N)
{
    const int idx = blockIdx.x * 256 + threadIdx.x;
    if (idx >= K * N) return;
    const int n = idx / K, k = idx - n * K;
    Wt[idx] = f2bf(W[(size_t)k * N + n]);
}

// ---------------------------------------------------------------------------
// proj_mfma: out_bf16 = bf16(A(Mx1280)@W + bias + pos_embed), plus confidence
// logits[row] += sum_c (A@W+bias)[row][c] * Wc[c]  (atomic; pre-pos values).
// BM=64, BN=256(full), BK=32.  4 waves; wave w owns cols w*64..w*64+63.
// A: fp32 reg-staged -> cvt_pk -> LDS [64][32] bf16 (shared by all waves).
// B: fragments straight from pre-transposed bf16 Wt[n][k] (L2-resident).
// MFMA mapping identical to the round-4-validated attn_mfma.
// grid (BNROWS/64), block 256.
// ---------------------------------------------------------------------------
__global__ __launch_bounds__(256)
void proj_mfma(const float* __restrict__ A, const ushort* __restrict__ Wt,
               const float* __restrict__ bias, const float* __restrict__ Wc,
               const float* __restrict__ xyz, ushort* __restrict__ out,
               float* __restrict__ logits)
{
    __shared__ ushort Al[64 * 32];   // [m][k] row-major bf16
    __shared__ float invfreq[42];
    const int t = threadIdx.x;
    const int lane = t & 63, w = t >> 6;
    const int col15 = lane & 15, sub = lane >> 4;
    const int m0 = blockIdx.x * 64;

    if (t < 42) invfreq[t] = __expf((float)(2 * t) * (-9.210340371976184f / 84.0f));

    f32x4 acc[4][4];
    #pragma unroll
    for (int s = 0; s < 4; ++s)
        #pragma unroll
        for (int u = 0; u < 4; ++u) acc[s][u] = (f32x4){0.f, 0.f, 0.f, 0.f};

    const float* Ag = A + (size_t)(m0 + (t >> 2)) * DIN + (t & 3) * 8;
    const ushort* Wg[4];
    #pragma unroll
    for (int u = 0; u < 4; ++u)
        Wg[u] = Wt + (size_t)(w * 64 + u * 16 + col15) * DIN + sub * 8;

    for (int k0 = 0; k0 < DIN; k0 += 32) {
        const float4 a0 = *(const float4*)(Ag + k0);
        const float4 a1 = *(const float4*)(Ag + k0 + 4);
        uint p[4];
        p[0] = cvtpk(a0.x, a0.y); p[1] = cvtpk(a0.z, a0.w);
        p[2] = cvtpk(a1.x, a1.y); p[3] = cvtpk(a1.z, a1.w);
        __syncthreads();                       // prior iter's reads complete
        *(uint4*)(Al + t * 8) = *(uint4*)p;    // [m=t/4][k=(t%4)*8..+7]
        __syncthreads();                       // tile visible
        bf16x8 bfr[4];
        #pragma unroll
        for (int u = 0; u < 4; ++u) bfr[u] = *(const bf16x8*)(Wg[u] + k0);
        #pragma unroll
        for (int s = 0; s < 4; ++s) {
            const bf16x8 af = *(const bf16x8*)(Al + (s * 16 + col15) * 32 + sub * 8);
            #pragma unroll
            for (int u = 0; u < 4; ++u)
                acc[s][u] = __builtin_amdgcn_mfma_f32_16x16x32_bf16(af, bfr[u], acc[s][u], 0, 0, 0);
        }
    }

    // epilogue: bias, confidence logits, pos-embed, bf16 store
    float bias_u[4], wc_u[4];
    int   cidx[4];
    #pragma unroll
    for (int u = 0; u < 4; ++u) {
        cidx[u]  = w * 64 + u * 16 + col15;
        bias_u[u] = bias[cidx[u]];
        wc_u[u]   = Wc[cidx[u]];
    }
    #pragma unroll
    for (int s = 0; s < 4; ++s) {
        #pragma unroll
        for (int r = 0; r < 4; ++r) {
            const int row = m0 + s * 16 + sub * 4 + r;
            const float px = xyz[(size_t)row * 3 + 0];
            const float py = xyz[(size_t)row * 3 + 1];
            const float pz = xyz[(size_t)row * 3 + 2];
            float wp = 0.f;
            #pragma unroll
            for (int u = 0; u < 4; ++u) {
                const int c = cidx[u];
                const float val = acc[s][u][r] + bias_u[u];
                wp = fmaf(val, wc_u[u], wp);
                float pv = 0.f;
                if (c < 252) {
                    const int coord = c / 84;
                    const int f = c - coord * 84;
                    const float xc = (coord == 0) ? px : ((coord == 1) ? py : pz);
                    const float vv = xc * 6.283185307179586f * invfreq[f >> 1];
                    pv = (f & 1) ? __cosf(vv) : __sinf(vv);
                }
                out[(size_t)row * DM + c] = f2bf(val + pv);
            }
            wp += __shfl_xor(wp, 1); wp += __shfl_xor(wp, 2);
            wp += __shfl_xor(wp, 4); wp += __shfl_xor(wp, 8);
            if (col15 == 0) atomicAdd(&logits[row], wp);
        }
    }
}

// ---------------------------------------------------------------------------
// qk_mfma: out_bf16 = bf16((A_bf16(Mx256) @ W + bias) * alpha)
// Same skeleton as proj_mfma, K=256, A already bf16.
// ---------------------------------------------------------------------------
__global__ __launch_bounds__(256)
void qk_mfma(const ushort* __restrict__ A, const ushort* __restrict__ Wt,
             const float* __restrict__ bias, const float alpha,
             ushort* __restrict__ out)
{
    __shared__ ushort Al[64 * 32];
    const int t = threadIdx.x;
    const int lane = t & 63, w = t >> 6;
    const int col15 = lane & 15, sub = lane >> 4;
    const int m0 = blockIdx.x * 64;

    f32x4 acc[4][4];
    #pragma unroll
    for (int s = 0; s < 4; ++s)
        #pragma unroll
        for (int u = 0; u < 4; ++u) acc[s][u] = (f32x4){0.f, 0.f, 0.f, 0.f};

    const ushort* Ag = A + (size_t)(m0 + (t >> 2)) * DM + (t & 3) * 8;
    const ushort* Wg[4];
    #pragma unroll
    for (int u = 0; u < 4; ++u)
        Wg[u] = Wt + (size_t)(w * 64 + u * 16 + col15) * DM + sub * 8;

    for (int k0 = 0; k0 < DM; k0 += 32) {
        const uint4 av = *(const uint4*)(Ag + k0);
        __syncthreads();
        *(uint4*)(Al + t * 8) = av;
        __syncthreads();
        bf16x8 bfr[4];
        #pragma unroll
        for (int u = 0; u < 4; ++u) bfr[u] = *(const bf16x8*)(Wg[u] + k0);
        #pragma unroll
        for (int s = 0; s < 4; ++s) {
            const bf16x8 af = *(const bf16x8*)(Al + (s * 16 + col15) * 32 + sub * 8);
            #pragma unroll
            for (int u = 0; u < 4; ++u)
                acc[s][u] = __builtin_amdgcn_mfma_f32_16x16x32_bf16(af, bfr[u], acc[s][u], 0, 0, 0);
        }
    }

    float bias_u[4];
    int cidx[4];
    #pragma unroll
    for (int u = 0; u < 4; ++u) {
        cidx[u] = w * 64 + u * 16 + col15;
        bias_u[u] = bias[cidx[u]];
    }
    #pragma unroll
    for (int s = 0; s < 4; ++s)
        #pragma unroll
        for (int r = 0; r < 4; ++r) {
            const int row = m0 + s * 16 + sub * 4 + r;
            #pragma unroll
            for (int u = 0; u < 4; ++u)
                out[(size_t)row * DM + cidx[u]] = f2bf((acc[s][u][r] + bias_u[u]) * alpha);
        }
}

// ---------------------------------------------------------------------------
// sigmoid_kernel: w[i] = sigmoid(w[i] + bc[0])
// ---------------------------------------------------------------------------
__global__ __launch_bounds__(256)
void sigmoid_kernel(float* __restrict__ w, const float* __restrict__ bc, int n)
{
    const int i = blockIdx.x * 256 + threadIdx.x;
    if (i < n) {
        const float z = w[i] + bc[0];
        w[i] = 1.0f / (1.0f + expf(-z));
    }
}

// ---------------------------------------------------------------------------
// attn_mfma: unchanged from round 4 (validated: absmax 0.0039).
// ---------------------------------------------------------------------------
__global__ __launch_bounds__(256, 2)
void attn_mfma(const ushort* __restrict__ Q, const ushort* __restrict__ K,
               const float* __restrict__ V, float* __restrict__ acc4)
{
    const int b    = blockIdx.y;
    const int lane = threadIdx.x & 63;
    const int wv   = threadIdx.x >> 6;
    const int col  = lane & 15;
    const int sub  = lane >> 4;
    const int qbase = blockIdx.x * 256 + wv * 64;
    const int k0    = blockIdx.z * 512;

    const ushort* Qb = Q + (size_t)b * NPTS * DM;
    const ushort* Kb = K + (size_t)b * NPTS * DM;
    const float*  Vb = V + (size_t)b * NPTS * 3;

    bf16x8 aq[4][8];
    #pragma unroll
    for (int s = 0; s < 4; ++s) {
        const ushort* qrow = Qb + (size_t)(qbase + s * 16 + col) * DM + sub * 8;
        #pragma unroll
        for (int c = 0; c < 8; ++c)
            aq[s][c] = *(const bf16x8*)(qrow + c * 32);
    }

    float lsum[4][4], ax[4][4], ay[4][4], az[4][4];
    #pragma unroll
    for (int s = 0; s < 4; ++s)
        #pragma unroll
        for (int r = 0; r < 4; ++r) {
            lsum[s][r] = 0.f; ax[s][r] = 0.f; ay[s][r] = 0.f; az[s][r] = 0.f;
        }

    for (int kt = k0; kt < k0 + 512; kt += 16) {
        const ushort* krow = Kb + (size_t)(kt + col) * DM + sub * 8;
        f32x4 sv0 = {0.f, 0.f, 0.f, 0.f};
        f32x4 sv1 = {0.f, 0.f, 0.f, 0.f};
        f32x4 sv2 = {0.f, 0.f, 0.f, 0.f};
        f32x4 sv3 = {0.f, 0.f, 0.f, 0.f};
        #pragma unroll
        for (int c = 0; c < 8; ++c) {
            const bf16x8 bk = *(const bf16x8*)(krow + c * 32);
            sv0 = __builtin_amdgcn_mfma_f32_16x16x32_bf16(aq[0][c], bk, sv0, 0, 0, 0);
            sv1 = __builtin_amdgcn_mfma_f32_16x16x32_bf16(aq[1][c], bk, sv1, 0, 0, 0);
            sv2 = __builtin_amdgcn_mfma_f32_16x16x32_bf16(aq[2][c], bk, sv2, 0, 0, 0);
            sv3 = __builtin_amdgcn_mfma_f32_16x16x32_bf16(aq[3][c], bk, sv3, 0, 0, 0);
        }
        const float vx = Vb[(size_t)(kt + col) * 3 + 0];
        const float vy = Vb[(size_t)(kt + col) * 3 + 1];
        const float vz = Vb[(size_t)(kt + col) * 3 + 2];
        #pragma unroll
        for (int r = 0; r < 4; ++r) {
            const float p0 = __expf(sv0[r] - 16.0f);
            const float p1 = __expf(sv1[r] - 16.0f);
            const float p2 = __expf(sv2[r] - 16.0f);
            const float p3 = __expf(sv3[r] - 16.0f);
            lsum[0][r] += p0; ax[0][r] = fmaf(p0, vx, ax[0][r]);
            ay[0][r] = fmaf(p0, vy, ay[0][r]); az[0][r] = fmaf(p0, vz, az[0][r]);
            lsum[1][r] += p1; ax[1][r] = fmaf(p1, vx, ax[1][r]);
            ay[1][r] = fmaf(p1, vy, ay[1][r]); az[1][r] = fmaf(p1, vz, az[1][r]);
            lsum[2][r] += p2; ax[2][r] = fmaf(p2, vx, ax[2][r]);
            ay[2][r] = fmaf(p2, vy, ay[2][r]); az[2][r] = fmaf(p2, vz, az[2][r]);
            lsum[3][r] += p3; ax[3][r] = fmaf(p3, vx, ax[3][r]);
            ay[3][r] = fmaf(p3, vy, ay[3][r]); az[3][r] = fmaf(p3, vz, az[3][r]);
        }
    }

    #pragma unroll
    for (int off = 1; off < 16; off <<= 1) {
        #pragma unroll
        for (int s = 0; s < 4; ++s)
            #pragma unroll
            for (int r = 0; r < 4; ++r) {
                lsum[s][r] += __shfl_xor(lsum[s][r], off);
                ax[s][r]   += __shfl_xor(ax[s][r], off);
                ay[s][r]   += __shfl_xor(ay[s][r], off);
                az[s][r]   += __shfl_xor(az[s][r], off);
            }
    }
    if (col == 0) {
        #pragma unroll
        for (int s = 0; s < 4; ++s)
            #pragma unroll
            for (int r = 0; r < 4; ++r) {
                const int row = qbase + s * 16 + sub * 4 + r;
                float* dst = acc4 + ((size_t)b * NPTS + row) * 4;
                atomicAdd(dst + 0, lsum[s][r]);
                atomicAdd(dst + 1, ax[s][r]);
                atomicAdd(dst + 2, ay[s][r]);
                atomicAdd(dst + 3, az[s][r]);
            }
    }
}

// ---------------------------------------------------------------------------
// reduce_kernel: per batch Kabsch sums (double), correspondences normalized
// inline from acc4 = {l, ax, ay, az}.
// ---------------------------------------------------------------------------
__global__ __launch_bounds__(256)
void reduce_kernel(const float* __restrict__ xyz1, const float* __restrict__ xyz2,
                   const float* __restrict__ sacc, const float* __restrict__ tacc,
                   const float* __restrict__ srcw, const float* __restrict__ tgtw,
                   double* __restrict__ bsums)
{
    const int b = blockIdx.x;
    const int t = threadIdx.x;
    double s[16];
    #pragma unroll
    for (int k = 0; k < 16; ++k) s[k] = 0.0;

    for (int i = t; i < 2 * NPTS; i += 256) {
        float ax_, ay_, az_, bx_, by_, bz_, w;
        if (i < NPTS) {
            const size_t row = (size_t)b * NPTS + i;
            ax_ = xyz1[row * 3]; ay_ = xyz1[row * 3 + 1]; az_ = xyz1[row * 3 + 2];
            const float4 s4 = *(const float4*)(sacc + row * 4);
            const float inv = 1.0f / s4.x;
            bx_ = s4.y * inv; by_ = s4.z * inv; bz_ = s4.w * inv;
            w = srcw[row];
        } else {
            const size_t row = (size_t)b * NPTS + (i - NPTS);
            const float4 t4 = *(const float4*)(tacc + row * 4);
            const float inv = 1.0f / t4.x;
            ax_ = t4.y * inv; ay_ = t4.z * inv; az_ = t4.w * inv;
            bx_ = xyz2[row * 3]; by_ = xyz2[row * 3 + 1]; bz_ = xyz2[row * 3 + 2];
            w = tgtw[row];
        }
        const double dw = (double)w;
        const double dax = ax_, day = ay_, daz = az_;
        const double dbx = bx_, dby = by_, dbz = bz_;
        s[0] += dw;
        s[1] += dw * dax; s[2] += dw * day; s[3] += dw * daz;
        s[4] += dw * dbx; s[5] += dw * dby; s[6] += dw * dbz;
        s[7]  += dw * dax * dbx; s[8]  += dw * dax * dby; s[9]  += dw * dax * dbz;
        s[10] += dw * day * dbx; s[11] += dw * day * dby; s[12] += dw * day * dbz;
        s[13] += dw * daz * dbx; s[14] += dw * daz * dby; s[15] += dw * daz * dbz;
    }

    __shared__ double red[256][16];
    #pragma unroll
    for (int k = 0; k < 16; ++k) red[t][k] = s[k];
    __syncthreads();
    for (int step = 128; step >= 1; step >>= 1) {
        if (t < step) {
            #pragma unroll
            for (int k = 0; k < 16; ++k) red[t][k] += red[t + step][k];
        }
        __syncthreads();
    }
    if (t == 0) {
        #pragma unroll
        for (int k = 0; k < 16; ++k) bsums[b * 16 + k] = red[0][k];
    }
}

// ---------------------------------------------------------------------------
// svd_kernel: per batch weighted Kabsch via double-precision Jacobi SVD(3x3).
// ---------------------------------------------------------------------------
__global__ void svd_kernel(const double* __restrict__ bsums, float* __restrict__ out)
{
    const int b = threadIdx.x;
    if (b >= NB) return;
    const double* s = bsums + b * 16;
    double Wd = s[0];
    if (Wd < 1e-6) Wd = 1e-6;
    const double inv = 1.0 / Wd;

    double ca[3], cb[3];
    for (int r = 0; r < 3; ++r) { ca[r] = s[1 + r] * inv; cb[r] = s[4 + r] * inv; }
    double cov[3][3];
    for (int r = 0; r < 3; ++r)
        for (int c = 0; c < 3; ++c)
            cov[r][c] = s[7 + r * 3 + c] * inv - ca[r] * cb[c];

    double Mm[3][3];
    for (int i = 0; i < 3; ++i)
        for (int j = 0; j < 3; ++j)
            Mm[i][j] = cov[0][i] * cov[0][j] + cov[1][i] * cov[1][j] + cov[2][i] * cov[2][j];

    double Vm[3][3] = {{1, 0, 0}, {0, 1, 0}, {0, 0, 1}};
    const int PP[3] = {0, 0, 1}, QQ[3] = {1, 2, 2};
    for (int sweep = 0; sweep < 20; ++sweep) {
        for (int pi = 0; pi < 3; ++pi) {
            const int p = PP[pi], q = QQ[pi];
            const double apq = Mm[p][q];
            if (fabs(apq) < 1e-300) continue;
            const double tau = (Mm[q][q] - Mm[p][p]) / (2.0 * apq);
            const double tt = ((tau >= 0.0) ? 1.0 : -1.0) / (fabs(tau) + sqrt(1.0 + tau * tau));
            const double c = 1.0 / sqrt(1.0 + tt * tt);
            const double sn = tt * c;
            for (int k = 0; k < 3; ++k) {
                const double mkp = Mm[k][p], mkq = Mm[k][q];
                Mm[k][p] = c * mkp - sn * mkq;
                Mm[k][q] = sn * mkp + c * mkq;
            }
            for (int k = 0; k < 3; ++k) {
                const double mpk = Mm[p][k], mqk = Mm[q][k];
                Mm[p][k] = c * mpk - sn * mqk;
                Mm[q][k] = sn * mpk + c * mqk;
            }
            for (int k = 0; k < 3; ++k) {
                const double vkp = Vm[k][p], vkq = Vm[k][q];
                Vm[k][p] = c * vkp - sn * vkq;
                Vm[k][q] = sn * vkp + c * vkq;
            }
        }
    }

    double l0 = Mm[0][0], l1 = Mm[1][1], l2 = Mm[2][2];
    double v0[3], v1[3], v2[3];
    for (int k = 0; k < 3; ++k) { v0[k] = Vm[k][0]; v1[k] = Vm[k][1]; v2[k] = Vm[k][2]; }
    if (l0 < l1) { double tmp = l0; l0 = l1; l1 = tmp;
        for (int k = 0; k < 3; ++k) { double tv = v0[k]; v0[k] = v1[k]; v1[k] = tv; } }
    if (l0 < l2) { double tmp = l0; l0 = l2; l2 = tmp;
        for (int k = 0; k < 3; ++k) { double tv = v0[k]; v0[k] = v2[k]; v2[k] = tv; } }
    if (l1 < l2) { double tmp = l1; l1 = l2; l2 = tmp;
        for (int k = 0; k < 3; ++k) { double tv = v1[k]; v1[k] = v2[k]; v2[k] = tv; } }

    double u0[3], u1[3], u2[3];
    for (int r = 0; r < 3; ++r) u0[r] = cov[r][0] * v0[0] + cov[r][1] * v0[1] + cov[r][2] * v0[2];
    for (int r = 0; r < 3; ++r) u1[r] = cov[r][0] * v1[0] + cov[r][1] * v1[1] + cov[r][2] * v1[2];
    double n0 = sqrt(u0[0] * u0[0] + u0[1] * u0[1] + u0[2] * u0[2]);
    if (n0 > 1e-30) { for (int k = 0; k < 3; ++k) u0[k] /= n0; }
    else { u0[0] = 1; u0[1] = 0; u0[2] = 0; }
    const double d01 = u0[0] * u1[0] + u0[1] * u1[1] + u0[2] * u1[2];
    for (int k = 0; k < 3; ++k) u1[k] -= d01 * u0[k];
    double n1 = sqrt(u1[0] * u1[0] + u1[1] * u1[1] + u1[2] * u1[2]);
    if (n1 > 1e-30) { for (int k = 0; k < 3; ++k) u1[k] /= n1; }
    else {
        const double aa0 = fabs(u0[0]), aa1 = fabs(u0[1]), aa2 = fabs(u0[2]);
        const int ax = (aa0 <= aa1 && aa0 <= aa2) ? 0 : ((aa1 <= aa2) ? 1 : 2);
        double e[3] = {0, 0, 0}; e[ax] = 1.0;
        const double d = u0[ax];
        for (int k = 0; k < 3; ++k) u1[k] = e[k] - d * u0[k];
        const double nn = sqrt(u1[0] * u1[0] + u1[1] * u1[1] + u1[2] * u1[2]);
        for (int k = 0; k < 3; ++k) u1[k] /= nn;
    }
    u2[0] = u0[1] * u1[2] - u0[2] * u1[1];
    u2[1] = u0[2] * u1[0] - u0[0] * u1[2];
    u2[2] = u0[0] * u1[1] - u0[1] * u1[0];

    double R[3][3];
    for (int r = 0; r < 3; ++r)
        for (int c = 0; c < 3; ++c)
            R[r][c] = v0[r] * u0[c] + v1[r] * u1[c] + v2[r] * u2[c];
    const double det = R[0][0] * (R[1][1] * R[2][2] - R[1][2] * R[2][1])
                     - R[0][1] * (R[1][0] * R[2][2] - R[1][2] * R[2][0])
                     + R[0][2] * (R[1][0] * R[2][1] - R[1][1] * R[2][0]);
    if (det <= 0.0) {
        for (int r = 0; r < 3; ++r)
            for (int c = 0; c < 3; ++c)
                R[r][c] -= 2.0 * v2[r] * u2[c];
    }
    double tv[3];
    for (int r = 0; r < 3; ++r)
        tv[r] = cb[r] - (R[r][0] * ca[0] + R[r][1] * ca[1] + R[r][2] * ca[2]);

    for (int r = 0; r < 3; ++r) {
        out[b * 12 + r * 4 + 0] = (float)R[r][0];
        out[b * 12 + r * 4 + 1] = (float)R[r][1];
        out[b * 12 + r * 4 + 2] = (float)R[r][2];
        out[b * 12 + r * 4 + 3] = (float)tv[r];
    }
}

// ---------------------------------------------------------------------------
extern "C" void kernel_launch(void* const* d_in, const int* in_sizes, int n_in,
                              void* d_out, int out_size, void* d_ws, size_t ws_size,
                              hipStream_t stream)
{
    const float* feat1 = (const float*)d_in[0];
    const float* xyz1  = (const float*)d_in[1];
    const float* feat2 = (const float*)d_in[2];
    const float* xyz2  = (const float*)d_in[3];
    const float* Wf = (const float*)d_in[4];
    const float* bf = (const float*)d_in[5];
    const float* Wq = (const float*)d_in[6];
    const float* bq = (const float*)d_in[7];
    const float* Wk = (const float*)d_in[8];
    const float* bk = (const float*)d_in[9];
    const float* Wc = (const float*)d_in[10];
    const float* bc = (const float*)d_in[11];
    float* out = (float*)d_out;

    // workspace layout
    float*  srcw = (float*)d_ws;                         // BNROWS   (zeroed)
    float*  tgtw = srcw + BNROWS;                        // BNROWS   (zeroed)
    float*  sacc = tgtw + BNROWS;                        // BNROWS*4 (zeroed)
    float*  tacc = sacc + (size_t)BNROWS * 4;            // BNROWS*4 (zeroed)
    double* bsums = (double*)(tacc + (size_t)BNROWS * 4);// 256 doubles (8B-aligned)
    ushort* src2 = (ushort*)(bsums + NB * 16);           // BNROWS*256 bf16
    ushort* tgt2 = src2 + (size_t)BNROWS * DM;
    ushort* qbuf = tgt2 + (size_t)BNROWS * DM;
    ushort* kbuf = qbuf + (size_t)BNROWS * DM;
    ushort* wft  = kbuf + (size_t)BNROWS * DM;           // 256*1280
    ushort* wqt  = wft + 256 * 1280;                     // 256*256
    ushort* wkt  = wqt + 256 * 256;                      // 256*256

    hipMemsetAsync(d_ws, 0, (size_t)10 * BNROWS * sizeof(float), stream);

    // transpose+convert weights to bf16 [n][k]
    convert_wt<<<(DIN * DM) / 256, 256, 0, stream>>>(Wf, wft, DIN, DM);
    convert_wt<<<(DM * DM) / 256, 256, 0, stream>>>(Wq, wqt, DM, DM);
    convert_wt<<<(DM * DM) / 256, 256, 0, stream>>>(Wk, wkt, DM, DM);

    const dim3 gm(BNROWS / 64);   // 512 blocks
    proj_mfma<<<gm, 256, 0, stream>>>(feat1, wft, bf, Wc, xyz1, src2, srcw);
    proj_mfma<<<gm, 256, 0, stream>>>(feat2, wft, bf, Wc, xyz2, tgt2, tgtw);
    sigmoid_kernel<<<(2 * BNROWS) / 256, 256, 0, stream>>>(srcw, bc, 2 * BNROWS);

    const float scale = 1.0f / 16.0f;  // 1/sqrt(256)
    const dim3 gattn(NPTS / 256, NB, 4);  // 512 blocks

    // direction 1: q from src2, k from tgt2, values xyz2 -> sacc
    qk_mfma<<<gm, 256, 0, stream>>>(src2, wqt, bq, scale, qbuf);
    qk_mfma<<<gm, 256, 0, stream>>>(tgt2, wkt, bk, 1.0f, kbuf);
    attn_mfma<<<gattn, 256, 0, stream>>>(qbuf, kbuf, xyz2, sacc);

    // direction 2: q from tgt2, k from src2, values xyz1 -> tacc
    qk_mfma<<<gm, 256, 0, stream>>>(tgt2, wqt, bq, scale, qbuf);
    qk_mfma<<<gm, 256, 0, stream>>>(src2, wkt, bk, 1.0f, kbuf);
    attn_mfma<<<gattn, 256, 0, stream>>>(qbuf, kbuf, xyz1, tacc);

    reduce_kernel<<<NB, 256, 0, stream>>>(xyz1, xyz2, sacc, tacc, srcw, tgtw, bsums);
    svd_kernel<<<1, 64, 0, stream>>>(bsums, out);
}